// Round 14
// baseline (581.769 us; speedup 1.0000x reference)
//
#include <hip/hip_runtime.h>
#include <hip/hip_bf16.h>
#include <stdint.h>

#define MEM_DIM 128
#define MSG_DIM 256
#define KTOT    384          // MSG_DIM + MEM_DIM
#define BM      64           // update rows per block
#define SLAB    (BM * KTOT * 2)   // 49152 B per LDS buffer

typedef __attribute__((ext_vector_type(8))) __bf16 bf16x8;
typedef __attribute__((ext_vector_type(4))) float  f32x4;

union B8u { uint32_t u[4]; bf16x8 v; };

__device__ __forceinline__ uint32_t cvt_pk(float lo, float hi) {
    uint32_t r;
    asm("v_cvt_pk_bf16_f32 %0, %1, %2" : "=v"(r) : "v"(lo), "v"(hi));
    return r;
}

__device__ __forceinline__ bf16x8 pack8(f32x4 a, f32x4 b) {
    B8u r;
    r.u[0] = cvt_pk(a.x, a.y);
    r.u[1] = cvt_pk(a.z, a.w);
    r.u[2] = cvt_pk(b.x, b.y);
    r.u[3] = cvt_pk(b.z, b.w);
    return r.v;
}

__device__ __forceinline__ bf16x8 load_cvt8(const float* __restrict__ p) {
    return pack8(*(const f32x4*)p, *(const f32x4*)(p + 4));
}

__device__ __forceinline__ float sigm(float x) {
    return __builtin_amdgcn_rcpf(1.0f + __expf(-x));
}
__device__ __forceinline__ float tanh_fast(float x) {
    return 1.0f - 2.0f * __builtin_amdgcn_rcpf(1.0f + __expf(2.0f * x));
}

// -------------------------------------- init: weight bf16 convert + bm zero
__global__ void init_kernel(const float* __restrict__ wih,
                            const float* __restrict__ whh,
                            __hip_bfloat16* __restrict__ wb,
                            uint32_t* __restrict__ bm, int bmwords) {
    int i = blockIdx.x * 256 + threadIdx.x;
    const int NIH = 3 * MEM_DIM * MSG_DIM;   // 98304
    const int NHH = 3 * MEM_DIM * MEM_DIM;   // 49152
    if (i < NIH)            wb[i] = __float2bfloat16(wih[i]);
    else if (i < NIH + NHH) wb[i] = __float2bfloat16(whh[i - NIH]);
    if (i < bmwords) bm[i] = 0;
}
__global__ void bm_set_kernel(const int* __restrict__ ids, uint32_t* __restrict__ bm, int U) {
    int i = blockIdx.x * 256 + threadIdx.x;
    if (i < U) {
        int id = ids[i];
        atomicOr(&bm[id >> 5], 1u << (id & 31));
    }
}

// ----------------------------------------------- copy kernel (skips updated)
__global__ void copy_skip_kernel(const f32x4* __restrict__ mem,
                                 const float* __restrict__ lu,
                                 f32x4* __restrict__ outm,
                                 float* __restrict__ outlu,
                                 const uint32_t* __restrict__ bm,
                                 int NN) {
    const int64_t n_mem_chunks = (int64_t)NN * 32;   // 512 B rows / 16 B
    const int64_t total = n_mem_chunks + NN;
    const int64_t stride = (int64_t)gridDim.x * blockDim.x;
    for (int64_t i = (int64_t)blockIdx.x * blockDim.x + threadIdx.x; i < total; i += stride) {
        if (i < n_mem_chunks) {
            int row = (int)(i >> 5);
            if (!((bm[row >> 5] >> (row & 31)) & 1u)) {
                f32x4 v = __builtin_nontemporal_load(&mem[i]);
                __builtin_nontemporal_store(v, &outm[i]);
            }
        } else {
            int node = (int)(i - n_mem_chunks);
            if (!((bm[node >> 5] >> (node & 31)) & 1u))
                outlu[node] = lu[node];
        }
    }
}

// fallback full copy (no workspace for bitmap)
__global__ void copy_all_kernel(const f32x4* __restrict__ mem,
                                const f32x4* __restrict__ lu,
                                f32x4* __restrict__ out,
                                int n_mem4, int n_tot4) {
    int stride = gridDim.x * blockDim.x;
    for (int i = blockIdx.x * blockDim.x + threadIdx.x; i < n_tot4; i += stride) {
        f32x4 v = (i < n_mem4) ? mem[i]
                               : __builtin_nontemporal_load(&lu[i - n_mem4]);
        __builtin_nontemporal_store(v, &out[i]);
    }
}

// ------------------------------------------------------- persistent GRU pipe
// 256 persistent blocks (1/CU), 512 threads = 8 waves, BM=64 rows/tile.
// Double-buffered At LDS (2 x 48KB). Per tile: ISSUE next tile's global
// loads (f32 in regs) -> k-loop on current buffer (FULL UNROLL: compiler
// hoists all 36 weight loads into flight) -> epilogue -> barrier ->
// convert+ds_write next tile -> barrier.  (T14 issue-early / write-late)
__device__ __forceinline__ int at_addr(int row, int kbyte) {
    return (row * (KTOT * 2) + kbyte) ^ ((row & 7) << 4);
}

template<bool PRE>
__global__ __launch_bounds__(512, 2)
void gru_pipe_kernel(const float* __restrict__ memory,
                     const int*   __restrict__ ids,
                     const float* __restrict__ msgs,
                     const float* __restrict__ ts,
                     const float* __restrict__ Wih,
                     const float* __restrict__ Whh,
                     const float* __restrict__ bih,
                     const float* __restrict__ bhh,
                     const __hip_bfloat16* __restrict__ WihB,  // [384][256]
                     const __hip_bfloat16* __restrict__ WhhB,  // [384][128]
                     float* __restrict__ out_mem,
                     float* __restrict__ out_lu,
                     int U, int ntiles) {
    __shared__ __align__(16) char At[2][SLAB];   // 98304 B

    const int tid  = threadIdx.x;
    const int w    = tid >> 6;
    const int lane = tid & 63;
    const int lq   = lane & 15;
    const int lk   = lane >> 4;

    // staging roles (fixed per thread)
    const int xr = tid >> 3, xseg = tid & 7;     // x: 8 threads/row, 32 f32 each
    // h reuses xr with 8 units of 16 f32 ... we use 2 units of 16B bf16 out

    // this lane's output column + biases (tile-invariant)
    const int c = w * 16 + lq;
    const float br  = bih[c] + bhh[c];
    const float bz  = bih[MEM_DIM + c] + bhh[MEM_DIM + c];
    const float bin = bih[2 * MEM_DIM + c];
    const float bhn = bhh[2 * MEM_DIM + c];

    // weight base pointers
    const __hip_bfloat16* wih_l = WihB + c * MSG_DIM + lk * 8;
    const __hip_bfloat16* whh_l = WhhB + c * MEM_DIM + lk * 8;
    const float* wih_f = Wih + c * MSG_DIM + lk * 8;
    const float* whh_f = Whh + c * MEM_DIM + lk * 8;

    // staged registers for the next tile (f32, converted at write time)
    f32x4 xa[8];
    f32x4 ha[4];

    auto ISSUE = [&](int t) {
        int rA = t * BM + xr; if (rA >= U) rA = U - 1;
        const float* xp = msgs + (size_t)rA * MSG_DIM + xseg * 32;
        #pragma unroll
        for (int i = 0; i < 8; ++i) xa[i] = *(const f32x4*)(xp + i * 4);
        const float* hp = memory + (size_t)ids[rA] * MEM_DIM + xseg * 16;
        #pragma unroll
        for (int i = 0; i < 4; ++i) ha[i] = *(const f32x4*)(hp + i * 4);
        // timestamp scatter for this tile
        if (tid < BM) {
            int r = t * BM + tid;
            if (r < U) out_lu[ids[r]] = ts[r];
        }
    };
    auto WRITE = [&](char* base) {
        #pragma unroll
        for (int i = 0; i < 4; ++i)
            *(bf16x8*)(base + at_addr(xr, xseg * 64 + i * 16)) =
                pack8(xa[2 * i], xa[2 * i + 1]);
        *(bf16x8*)(base + at_addr(xr, 512 + xseg * 32))      = pack8(ha[0], ha[1]);
        *(bf16x8*)(base + at_addr(xr, 512 + xseg * 32 + 16)) = pack8(ha[2], ha[3]);
    };

    int t = blockIdx.x;
    if (t >= ntiles) return;

    // prologue: stage tile t into buffer 0
    ISSUE(t);
    WRITE(At[0]);
    __syncthreads();

    int cur = 0;
    for (; t < ntiles; t += gridDim.x, cur ^= 1) {
        const int tn = t + gridDim.x;
        const bool hasnext = (tn < ntiles);
        if (hasnext) ISSUE(tn);          // loads fly during the k-loop below

        char* base = At[cur];
        const f32x4 z4 = {0.f, 0.f, 0.f, 0.f};
        f32x4 acc[4][4];
        #pragma unroll
        for (int m = 0; m < 4; ++m)
            #pragma unroll
            for (int q = 0; q < 4; ++q) acc[m][q] = z4;

        // ---------- phase X: W_ih, 8 k-steps (FULL UNROLL)
        #pragma unroll
        for (int ks = 0; ks < 8; ++ks) {
            bf16x8 bv0, bv1, bv2;
            if (PRE) {
                bv0 = *(const bf16x8*)(wih_l + 0 * 128 * MSG_DIM + ks * 32);
                bv1 = *(const bf16x8*)(wih_l + 1 * 128 * MSG_DIM + ks * 32);
                bv2 = *(const bf16x8*)(wih_l + 2 * 128 * MSG_DIM + ks * 32);
            } else {
                bv0 = load_cvt8(wih_f + 0 * 128 * MSG_DIM + ks * 32);
                bv1 = load_cvt8(wih_f + 1 * 128 * MSG_DIM + ks * 32);
                bv2 = load_cvt8(wih_f + 2 * 128 * MSG_DIM + ks * 32);
            }
            bf16x8 af[4];
            #pragma unroll
            for (int m = 0; m < 4; ++m)
                af[m] = *(const bf16x8*)(base + at_addr(m * 16 + lq, ks * 64 + lk * 16));
            #pragma unroll
            for (int m = 0; m < 4; ++m)
                acc[m][0] = __builtin_amdgcn_mfma_f32_16x16x32_bf16(af[m], bv0, acc[m][0], 0, 0, 0);
            #pragma unroll
            for (int m = 0; m < 4; ++m)
                acc[m][1] = __builtin_amdgcn_mfma_f32_16x16x32_bf16(af[m], bv1, acc[m][1], 0, 0, 0);
            #pragma unroll
            for (int m = 0; m < 4; ++m)
                acc[m][2] = __builtin_amdgcn_mfma_f32_16x16x32_bf16(af[m], bv2, acc[m][2], 0, 0, 0);
        }
        // ---------- phase H: W_hh, 4 k-steps (FULL UNROLL)
        #pragma unroll
        for (int ks = 0; ks < 4; ++ks) {
            bf16x8 bv0, bv1, bv2;
            if (PRE) {
                bv0 = *(const bf16x8*)(whh_l + 0 * 128 * MEM_DIM + ks * 32);
                bv1 = *(const bf16x8*)(whh_l + 1 * 128 * MEM_DIM + ks * 32);
                bv2 = *(const bf16x8*)(whh_l + 2 * 128 * MEM_DIM + ks * 32);
            } else {
                bv0 = load_cvt8(whh_f + 0 * 128 * MEM_DIM + ks * 32);
                bv1 = load_cvt8(whh_f + 1 * 128 * MEM_DIM + ks * 32);
                bv2 = load_cvt8(whh_f + 2 * 128 * MEM_DIM + ks * 32);
            }
            bf16x8 af[4];
            #pragma unroll
            for (int m = 0; m < 4; ++m)
                af[m] = *(const bf16x8*)(base + at_addr(m * 16 + lq, 512 + ks * 64 + lk * 16));
            #pragma unroll
            for (int m = 0; m < 4; ++m)
                acc[m][0] = __builtin_amdgcn_mfma_f32_16x16x32_bf16(af[m], bv0, acc[m][0], 0, 0, 0);
            #pragma unroll
            for (int m = 0; m < 4; ++m)
                acc[m][1] = __builtin_amdgcn_mfma_f32_16x16x32_bf16(af[m], bv1, acc[m][1], 0, 0, 0);
            #pragma unroll
            for (int m = 0; m < 4; ++m)
                acc[m][3] = __builtin_amdgcn_mfma_f32_16x16x32_bf16(af[m], bv2, acc[m][3], 0, 0, 0);
        }

        // ---------- epilogue: gate math + scatter (h_old from current buffer)
        #pragma unroll
        for (int m = 0; m < 4; ++m) {
            #pragma unroll
            for (int j = 0; j < 4; ++j) {
                int row = m * 16 + lk * 4 + j;
                int r = t * BM + row;
                if (r < U) {
                    int id = ids[r];
                    float hold = __bfloat162float(
                        *(const __hip_bfloat16*)(base + at_addr(row, 512 + c * 2)));
                    float rg = sigm(acc[m][0][j] + br);
                    float zg = sigm(acc[m][1][j] + bz);
                    float ng = tanh_fast(acc[m][2][j] + bin + rg * (acc[m][3][j] + bhn));
                    out_mem[(size_t)id * MEM_DIM + c] = (1.0f - zg) * ng + zg * hold;
                }
            }
        }

        __syncthreads();                 // all waves done reading buffers
        if (hasnext) WRITE(At[cur ^ 1]); // convert + store next tile
        __syncthreads();                 // next buffer ready
    }
}

// ------------------------------------------------------------------- launcher
extern "C" void kernel_launch(void* const* d_in, const int* in_sizes, int n_in,
                              void* d_out, int out_size, void* d_ws, size_t ws_size,
                              hipStream_t stream) {
    const float* memory      = (const float*)d_in[0];
    const float* last_update = (const float*)d_in[1];
    const int*   ids         = (const int*)  d_in[2];
    const float* msgs        = (const float*)d_in[3];
    const float* ts          = (const float*)d_in[4];
    const float* Wih         = (const float*)d_in[5];
    const float* Whh         = (const float*)d_in[6];
    const float* bih         = (const float*)d_in[7];
    const float* bhh         = (const float*)d_in[8];

    const int NN = in_sizes[1];          // 1,000,000 nodes
    const int U  = in_sizes[2];          // 200,000 updates

    float* out_mem = (float*)d_out;
    float* out_lu  = out_mem + (size_t)NN * MEM_DIM;

    const int NIH = 3 * MEM_DIM * MSG_DIM;                    // 98304
    const int NHH = 3 * MEM_DIM * MEM_DIM;                    // 49152
    const size_t WBYTES  = (size_t)(NIH + NHH) * sizeof(__hip_bfloat16);  // 294912
    const size_t BM_OFF  = (WBYTES + 255) & ~(size_t)255;
    const int    BMWORDS = (NN + 31) / 32;
    const int    ntiles  = (U + BM - 1) / BM;                 // 3125

    if (ws_size >= BM_OFF + (size_t)BMWORDS * 4) {
        __hip_bfloat16* wb = (__hip_bfloat16*)d_ws;
        uint32_t* bm = (uint32_t*)((char*)d_ws + BM_OFF);

        int initn = (NIH + NHH > BMWORDS) ? (NIH + NHH) : BMWORDS;
        init_kernel<<<(initn + 255) / 256, 256, 0, stream>>>(Wih, Whh, wb, bm, BMWORDS);
        bm_set_kernel<<<(U + 255) / 256, 256, 0, stream>>>(ids, bm, U);

        gru_pipe_kernel<true><<<256, 512, 0, stream>>>(
            memory, ids, msgs, ts, Wih, Whh, bih, bhh,
            wb, wb + NIH, out_mem, out_lu, U, ntiles);

        copy_skip_kernel<<<8192, 256, 0, stream>>>((const f32x4*)memory, last_update,
                                                   (f32x4*)out_mem, out_lu, bm, NN);
    } else {
        int n_mem4 = NN * MEM_DIM / 4;
        int n_tot4 = n_mem4 + NN / 4;
        copy_all_kernel<<<8192, 256, 0, stream>>>((const f32x4*)memory,
                                                  (const f32x4*)last_update,
                                                  (f32x4*)d_out, n_mem4, n_tot4);
        gru_pipe_kernel<false><<<256, 512, 0, stream>>>(
            memory, ids, msgs, ts, Wih, Whh, bih, bhh,
            nullptr, nullptr, out_mem, out_lu, U, ntiles);
    }
}

// Round 15
// 403.830 us; speedup vs baseline: 1.4406x; 1.4406x over previous
//
#include <hip/hip_runtime.h>
#include <hip/hip_bf16.h>
#include <stdint.h>

#define MEM_DIM 128
#define MSG_DIM 256
#define KTOT    384          // MSG_DIM + MEM_DIM
#define BM      64           // update rows per block
#define NCOPY   2048         // copy-role blocks

typedef __attribute__((ext_vector_type(8))) __bf16 bf16x8;
typedef __attribute__((ext_vector_type(4))) float  f32x4;

union B8u { uint32_t u[4]; bf16x8 v; };

__device__ __forceinline__ uint32_t cvt_pk(float lo, float hi) {
    uint32_t r;
    asm("v_cvt_pk_bf16_f32 %0, %1, %2" : "=v"(r) : "v"(lo), "v"(hi));
    return r;
}

__device__ __forceinline__ bf16x8 load_cvt8(const float* __restrict__ p) {
    f32x4 a = *(const f32x4*)p;
    f32x4 b = *(const f32x4*)(p + 4);
    B8u r;
    r.u[0] = cvt_pk(a.x, a.y);
    r.u[1] = cvt_pk(a.z, a.w);
    r.u[2] = cvt_pk(b.x, b.y);
    r.u[3] = cvt_pk(b.z, b.w);
    return r.v;
}

__device__ __forceinline__ float sigm(float x) {
    return __builtin_amdgcn_rcpf(1.0f + __expf(-x));
}
__device__ __forceinline__ float tanh_fast(float x) {
    return 1.0f - 2.0f * __builtin_amdgcn_rcpf(1.0f + __expf(2.0f * x));
}

// -------------------------------------- init: weight bf16 convert + bm zero
__global__ void init_kernel(const float* __restrict__ wih,
                            const float* __restrict__ whh,
                            __hip_bfloat16* __restrict__ wb,
                            uint32_t* __restrict__ bm, int bmwords) {
    int i = blockIdx.x * 256 + threadIdx.x;
    const int NIH = 3 * MEM_DIM * MSG_DIM;   // 98304
    const int NHH = 3 * MEM_DIM * MEM_DIM;   // 49152
    if (i < NIH)            wb[i] = __float2bfloat16(wih[i]);
    else if (i < NIH + NHH) wb[i] = __float2bfloat16(whh[i - NIH]);
    if (i < bmwords) bm[i] = 0;
}
__global__ void bm_set_kernel(const int* __restrict__ ids, uint32_t* __restrict__ bm, int U) {
    int i = blockIdx.x * 256 + threadIdx.x;
    if (i < U) {
        int id = ids[i];
        atomicOr(&bm[id >> 5], 1u << (id & 31));
    }
}

// fallback full copy (no workspace for bitmap)
__global__ void copy_all_kernel(const f32x4* __restrict__ mem,
                                const f32x4* __restrict__ lu,
                                f32x4* __restrict__ out,
                                int n_mem4, int n_tot4) {
    int stride = gridDim.x * blockDim.x;
    for (int i = blockIdx.x * blockDim.x + threadIdx.x; i < n_tot4; i += stride) {
        f32x4 v = (i < n_mem4) ? mem[i]
                               : __builtin_nontemporal_load(&lu[i - n_mem4]);
        __builtin_nontemporal_store(v, &out[i]);
    }
}

// -------------------------------------------------- mixed GRU + copy kernel
// Top-level role branch on blockIdx: GEMM blocks run the EXACT R8 body
// (BM=64, 8 waves, At LDS, B streamed global->MFMA); copy blocks run the
// bitmap-skip passthrough. Bresenham interleave in dispatch order => every
// CU hosts latency-bound (GEMM) + BW-bound (copy) blocks concurrently
// (m114: co-scheduled waves overlap, time ~= max not sum). No atomics, no
// cross-path live state, no shared vmcnt queues.
__device__ __forceinline__ int at_addr(int row, int kbyte) {
    return (row * (KTOT * 2) + kbyte) ^ ((row & 7) << 4);
}

template<bool PRE>
__global__ __launch_bounds__(512, 4)
void gru_mix_kernel(const float* __restrict__ memory,
                    const int*   __restrict__ ids,
                    const float* __restrict__ msgs,
                    const float* __restrict__ ts,
                    const float* __restrict__ Wih,
                    const float* __restrict__ Whh,
                    const float* __restrict__ bih,
                    const float* __restrict__ bhh,
                    const __hip_bfloat16* __restrict__ WihB,  // [384][256]
                    const __hip_bfloat16* __restrict__ WhhB,  // [384][128]
                    const uint32_t* __restrict__ bm,
                    const float* __restrict__ last_update,
                    float* __restrict__ out_mem,
                    float* __restrict__ out_lu,
                    int U, int ntiles, int total, int NN) {
    __shared__ __align__(16) char At[BM * KTOT * 2];   // 49152 B

    const int bid = blockIdx.x;
    const int tid = threadIdx.x;

    // Bresenham role split: exactly ntiles GEMM slots, uniformly interleaved
    const int64_t g0 = ((int64_t)bid * ntiles) / total;
    const int64_t g1 = ((int64_t)(bid + 1) * ntiles) / total;

    if (g1 > g0) {
        // ======================= GEMM role (tile = g0) =======================
        const int t    = (int)g0;
        const int w    = tid >> 6;
        const int lane = tid & 63;
        const int lq   = lane & 15;
        const int lk   = lane >> 4;
        const int rb   = t * BM;

        // ---- timestamp scatter
        if (tid < BM) {
            int r = rb + tid;
            if (r < U) out_lu[ids[r]] = ts[r];
        }

        // ---- stage At: x part (512 threads, 8 segs of 32 f32 per row)
        {
            int r = tid >> 3, seg = tid & 7;
            int rA = rb + r; if (rA >= U) rA = U - 1;
            const float* xp = msgs + (size_t)rA * MSG_DIM + seg * 32;
            #pragma unroll
            for (int i = 0; i < 4; ++i)
                *(bf16x8*)(At + at_addr(r, seg * 64 + i * 16)) = load_cvt8(xp + i * 8);
        }
        // ---- stage At: h part (512 threads, 8 units of 16 f32 per row)
        {
            int r = tid >> 3, u = tid & 7;
            int rA = rb + r; if (rA >= U) rA = U - 1;
            const float* hp = memory + (size_t)ids[rA] * MEM_DIM + u * 16;
            *(bf16x8*)(At + at_addr(r, 512 + u * 32))      = load_cvt8(hp);
            *(bf16x8*)(At + at_addr(r, 512 + u * 32 + 16)) = load_cvt8(hp + 8);
        }

        // this lane's output column + biases
        const int c = w * 16 + lq;
        const float br  = bih[c] + bhh[c];
        const float bz  = bih[MEM_DIM + c] + bhh[MEM_DIM + c];
        const float bin = bih[2 * MEM_DIM + c];
        const float bhn = bhh[2 * MEM_DIM + c];

        // per-lane weight base pointers
        const __hip_bfloat16* wih_l = WihB + c * MSG_DIM + lk * 8;
        const __hip_bfloat16* whh_l = WhhB + c * MEM_DIM + lk * 8;
        const float* wih_f = Wih + c * MSG_DIM + lk * 8;
        const float* whh_f = Whh + c * MEM_DIM + lk * 8;

        const f32x4 z4 = {0.f, 0.f, 0.f, 0.f};
        f32x4 acc[4][4];
        #pragma unroll
        for (int m = 0; m < 4; ++m)
            #pragma unroll
            for (int q = 0; q < 4; ++q) acc[m][q] = z4;

        __syncthreads();   // At ready

        // ---------------- phase X: W_ih, 8 k-steps, gates r,z,i_n
        #pragma unroll 1
        for (int ks = 0; ks < 8; ++ks) {
            bf16x8 bv0, bv1, bv2;
            if (PRE) {
                bv0 = *(const bf16x8*)(wih_l + 0 * 128 * MSG_DIM + ks * 32);
                bv1 = *(const bf16x8*)(wih_l + 1 * 128 * MSG_DIM + ks * 32);
                bv2 = *(const bf16x8*)(wih_l + 2 * 128 * MSG_DIM + ks * 32);
            } else {
                bv0 = load_cvt8(wih_f + 0 * 128 * MSG_DIM + ks * 32);
                bv1 = load_cvt8(wih_f + 1 * 128 * MSG_DIM + ks * 32);
                bv2 = load_cvt8(wih_f + 2 * 128 * MSG_DIM + ks * 32);
            }
            bf16x8 af[4];
            #pragma unroll
            for (int m = 0; m < 4; ++m)
                af[m] = *(const bf16x8*)(At + at_addr(m * 16 + lq, ks * 64 + lk * 16));
            #pragma unroll
            for (int m = 0; m < 4; ++m)
                acc[m][0] = __builtin_amdgcn_mfma_f32_16x16x32_bf16(af[m], bv0, acc[m][0], 0, 0, 0);
            #pragma unroll
            for (int m = 0; m < 4; ++m)
                acc[m][1] = __builtin_amdgcn_mfma_f32_16x16x32_bf16(af[m], bv1, acc[m][1], 0, 0, 0);
            #pragma unroll
            for (int m = 0; m < 4; ++m)
                acc[m][2] = __builtin_amdgcn_mfma_f32_16x16x32_bf16(af[m], bv2, acc[m][2], 0, 0, 0);
        }
        // ---------------- phase H: W_hh, 4 k-steps, gates r,z,h_n
        #pragma unroll 1
        for (int ks = 0; ks < 4; ++ks) {
            bf16x8 bv0, bv1, bv2;
            if (PRE) {
                bv0 = *(const bf16x8*)(whh_l + 0 * 128 * MEM_DIM + ks * 32);
                bv1 = *(const bf16x8*)(whh_l + 1 * 128 * MEM_DIM + ks * 32);
                bv2 = *(const bf16x8*)(whh_l + 2 * 128 * MEM_DIM + ks * 32);
            } else {
                bv0 = load_cvt8(whh_f + 0 * 128 * MEM_DIM + ks * 32);
                bv1 = load_cvt8(whh_f + 1 * 128 * MEM_DIM + ks * 32);
                bv2 = load_cvt8(whh_f + 2 * 128 * MEM_DIM + ks * 32);
            }
            bf16x8 af[4];
            #pragma unroll
            for (int m = 0; m < 4; ++m)
                af[m] = *(const bf16x8*)(At + at_addr(m * 16 + lq, 512 + ks * 64 + lk * 16));
            #pragma unroll
            for (int m = 0; m < 4; ++m)
                acc[m][0] = __builtin_amdgcn_mfma_f32_16x16x32_bf16(af[m], bv0, acc[m][0], 0, 0, 0);
            #pragma unroll
            for (int m = 0; m < 4; ++m)
                acc[m][1] = __builtin_amdgcn_mfma_f32_16x16x32_bf16(af[m], bv1, acc[m][1], 0, 0, 0);
            #pragma unroll
            for (int m = 0; m < 4; ++m)
                acc[m][3] = __builtin_amdgcn_mfma_f32_16x16x32_bf16(af[m], bv2, acc[m][3], 0, 0, 0);
        }

        // ---- epilogue: gate math + scatter (h_old read back from At)
        #pragma unroll
        for (int m = 0; m < 4; ++m) {
            #pragma unroll
            for (int j = 0; j < 4; ++j) {
                int row = m * 16 + lk * 4 + j;
                int r = rb + row;
                if (r < U) {
                    int id = ids[r];
                    float hold = __bfloat162float(
                        *(const __hip_bfloat16*)(At + at_addr(row, 512 + c * 2)));
                    float rg = sigm(acc[m][0][j] + br);
                    float zg = sigm(acc[m][1][j] + bz);
                    float ng = tanh_fast(acc[m][2][j] + bin + rg * (acc[m][3][j] + bhn));
                    out_mem[(size_t)id * MEM_DIM + c] = (1.0f - zg) * ng + zg * hold;
                }
            }
        }
    } else {
        // ======================= copy role =======================
        const int64_t ncopy = total - ntiles;
        const int64_t ord   = bid - g0;                 // 0 .. ncopy-1
        const int64_t n_mem_chunks = (int64_t)NN * 32;  // 512 B rows / 16 B
        const int64_t tot = n_mem_chunks + NN;
        const int64_t stride = ncopy * 512;
        const f32x4* memv = (const f32x4*)memory;
        f32x4* outv = (f32x4*)out_mem;
        for (int64_t i = ord * 512 + tid; i < tot; i += stride) {
            if (i < n_mem_chunks) {
                int row = (int)(i >> 5);
                if (!((bm[row >> 5] >> (row & 31)) & 1u)) {
                    f32x4 v = __builtin_nontemporal_load(&memv[i]);
                    __builtin_nontemporal_store(v, &outv[i]);
                }
            } else {
                int node = (int)(i - n_mem_chunks);
                if (!((bm[node >> 5] >> (node & 31)) & 1u))
                    out_lu[node] = last_update[node];
            }
        }
    }
}

// ------------------------------------------------------------------- launcher
extern "C" void kernel_launch(void* const* d_in, const int* in_sizes, int n_in,
                              void* d_out, int out_size, void* d_ws, size_t ws_size,
                              hipStream_t stream) {
    const float* memory      = (const float*)d_in[0];
    const float* last_update = (const float*)d_in[1];
    const int*   ids         = (const int*)  d_in[2];
    const float* msgs        = (const float*)d_in[3];
    const float* ts          = (const float*)d_in[4];
    const float* Wih         = (const float*)d_in[5];
    const float* Whh         = (const float*)d_in[6];
    const float* bih         = (const float*)d_in[7];
    const float* bhh         = (const float*)d_in[8];

    const int NN = in_sizes[1];          // 1,000,000 nodes
    const int U  = in_sizes[2];          // 200,000 updates

    float* out_mem = (float*)d_out;
    float* out_lu  = out_mem + (size_t)NN * MEM_DIM;

    const int NIH = 3 * MEM_DIM * MSG_DIM;                    // 98304
    const int NHH = 3 * MEM_DIM * MEM_DIM;                    // 49152
    const size_t WBYTES  = (size_t)(NIH + NHH) * sizeof(__hip_bfloat16);  // 294912
    const size_t BM_OFF  = (WBYTES + 255) & ~(size_t)255;
    const int    BMWORDS = (NN + 31) / 32;
    const int    ntiles  = (U + BM - 1) / BM;                 // 3125
    const int    total   = ntiles + NCOPY;                    // 5173

    if (ws_size >= BM_OFF + (size_t)BMWORDS * 4) {
        __hip_bfloat16* wb = (__hip_bfloat16*)d_ws;
        uint32_t* bm = (uint32_t*)((char*)d_ws + BM_OFF);

        int initn = (NIH + NHH > BMWORDS) ? (NIH + NHH) : BMWORDS;
        init_kernel<<<(initn + 255) / 256, 256, 0, stream>>>(Wih, Whh, wb, bm, BMWORDS);
        bm_set_kernel<<<(U + 255) / 256, 256, 0, stream>>>(ids, bm, U);

        gru_mix_kernel<true><<<total, 512, 0, stream>>>(
            memory, ids, msgs, ts, Wih, Whh, bih, bhh,
            wb, wb + NIH, bm, last_update, out_mem, out_lu, U, ntiles, total, NN);
    } else {
        // fallback: full copy first, then GEMM-only (total == ntiles -> all
        // blocks take the GEMM branch; copy handled by copy_all)
        int n_mem4 = NN * MEM_DIM / 4;
        int n_tot4 = n_mem4 + NN / 4;
        copy_all_kernel<<<8192, 256, 0, stream>>>((const f32x4*)memory,
                                                  (const f32x4*)last_update,
                                                  (f32x4*)d_out, n_mem4, n_tot4);
        gru_mix_kernel<false><<<ntiles, 512, 0, stream>>>(
            memory, ids, msgs, ts, Wih, Whh, bih, bhh,
            nullptr, nullptr, nullptr, last_update, out_mem, out_lu,
            U, ntiles, ntiles, NN);
    }
}